// Round 1
// 326.485 us; speedup vs baseline: 1.1080x; 1.1080x over previous
//
#include <hip/hip_runtime.h>

#define SEQ   200
#define BATCH 4096
#define EMB   100
#define HID   300
#define NH1   256
#define BM    16
#define NFRAG 13             // K = 416: xe k=0..99 | zeros 100..111 | h k=112..411 | zeros
#define FRB   14             // allocated frag blocks (k up to 447)
#define FB    1024           // bytes per frag block (32 k x 16 rows x 2B)
#define BUFB  (FRB * FB)
#define NTMAX 3
#define NHF   10
#define H1P   260
#define PD    10             // LDS read-pipeline depth

typedef _Float16 half8 __attribute__((ext_vector_type(8)));
typedef _Float16 half4h __attribute__((ext_vector_type(4)));
typedef float floatx4 __attribute__((ext_vector_type(4)));

__device__ __forceinline__ float fast_tanh(float x) {
    float e = __expf(2.0f * x);
    float r = __builtin_amdgcn_rcpf(e + 1.0f);
    return 1.0f - 2.0f * r;
}

// frag-space byte offset of (batch row m, combined-k k)
__device__ __forceinline__ int fragoff(int m, int k) {
    return (k >> 5) * FB + ((k >> 3) & 3) * 256 + m * 16 + (k & 7) * 2;
}

// One straight-line recurrent loop, NTT = compile-time tiles/wave.
// Schedule per timestep t:
//   1. issue af ds_reads (PD deep)
//   2. store pf (= xe(t+1), global-loaded at t-1) into wb  [full-iteration slack]
//   3. issue gather of xe(t+2) into pf                      [in flight across the barrier]
//   4. MFMA chains (bias fed as C of first MFMA)
//   5. tanh + h stores
//   6. lgkmcnt(0)-only barrier — vmcnt NOT drained, so the gather rides through
#define T_LOOP(NTT)                                                                   \
    _Pragma("unroll 2")                                                               \
    for (int t = 0; t < SEQ; ++t) {                                                   \
        const int p = t & 1;                                                          \
        const char* rb = ub + p * BUFB + rdo;                                         \
        char*       wb = ub + (1 - p) * BUFB;                                         \
        half8 af[NFRAG];                                                              \
        _Pragma("unroll")                                                             \
        for (int kk = 0; kk < PD; ++kk) af[kk] = *(const half8*)(rb + kk * FB);       \
        if (is_st && (t + 1 < SEQ)) {                                                 \
            half4h hv; hv[0] = (_Float16)pf.x; hv[1] = (_Float16)pf.y;                \
                       hv[2] = (_Float16)pf.z; hv[3] = (_Float16)pf.w;                \
            *(half4h*)(wb + xwo) = hv;                                                \
        }                                                                             \
        if (is_st && (t + 2 < SEQ)) {                                                 \
            const int idx = xs[(t + 2) * BM + gr];                                    \
            pf = ((const float4*)emb)[idx * 25 + gc];                                 \
        }                                                                             \
        floatx4 acc[NTT];                                                             \
        _Pragma("unroll")                                                             \
        for (int kk = 0; kk < NFRAG; ++kk) {                                          \
            if (kk + PD < NFRAG) af[kk + PD] = *(const half8*)(rb + (kk + PD) * FB);  \
            _Pragma("unroll")                                                         \
            for (int tt = 0; tt < NTT; ++tt)                                          \
                acc[tt] = __builtin_amdgcn_mfma_f32_16x16x32_f16(                     \
                    Wb[tt][kk], af[kk], (kk == 0) ? biasv[tt] : acc[tt], 0, 0, 0);    \
        }                                                                             \
        _Pragma("unroll")                                                             \
        for (int tt = 0; tt < NTT; ++tt) {                                            \
            half4h hv;                                                                \
            _Pragma("unroll")                                                         \
            for (int r = 0; r < 4; ++r) hv[r] = (_Float16)fast_tanh(acc[tt][r]);      \
            *(half4h*)(wb + hwo[tt]) = hv;                                            \
        }                                                                             \
        asm volatile("s_waitcnt lgkmcnt(0)" ::: "memory");                            \
        __builtin_amdgcn_s_barrier();                                                 \
    }

__global__ void __launch_bounds__(512)
rnn_fused(const int* __restrict__ x, const float* __restrict__ emb,
          const float* __restrict__ W_ih, const float* __restrict__ b_ih,
          const float* __restrict__ W_hh, const float* __restrict__ b_hh,
          const float* __restrict__ W1, const float* __restrict__ b1,
          const float* __restrict__ W2, const float* __restrict__ b2,
          float* __restrict__ out)
{
    __shared__ __align__(16) _Float16 uf[2][FRB][512];  // frag-order, double-buffered
    __shared__ int   xs[SEQ * BM];
    __shared__ float h1s[BM][H1P];

    const int tid  = threadIdx.x;
    const int lane = tid & 63;
    const int w    = tid >> 6;
    const int ln15 = lane & 15;
    const int q    = lane >> 4;
    const int row0 = blockIdx.x * BM;

    // 19 tiles of 16 cols: waves 0-2 get 3, waves 3-7 get 2
    const int t0 = (w < 3) ? 3 * w : 2 * w + 3;

    for (int i = tid; i < 2 * FRB * 512 / 2; i += 512) ((unsigned int*)uf)[i] = 0u;
    for (int i = tid; i < SEQ * BM; i += 512)
        xs[i] = x[(size_t)(i >> 4) * BATCH + row0 + (i & 15)];

    // ---- W resident in registers (A-operand: lane ln15 = row n, k = kk*32+q*8+j)
    half8   Wb[NTMAX][NFRAG];
    floatx4 biasv[NTMAX];
#pragma unroll
    for (int tt = 0; tt < NTMAX; ++tt) {
        const int nb = (t0 + tt) * 16;
#pragma unroll
        for (int r = 0; r < 4; ++r) {
            const int col = nb + 4 * q + r;
            biasv[tt][r] = (col < HID) ? (b_ih[col] + b_hh[col]) : 0.0f;
        }
        const int n = nb + ln15;
#pragma unroll
        for (int kk = 0; kk < NFRAG; ++kk) {
            union { half8 h; unsigned int d[4]; } cv;
#pragma unroll
            for (int j = 0; j < 8; ++j) {
                const int k = kk * 32 + q * 8 + j;
                float v = 0.0f;
                if (n < HID) {
                    if (k < EMB)                        v = W_ih[n * EMB + k];
                    else if (k >= 112 && k < 112 + HID) v = W_hh[n * HID + (k - 112)];
                }
                cv.h[j] = (_Float16)v;
            }
            asm volatile("" : "+v"(cv.d[0]), "+v"(cv.d[1]), "+v"(cv.d[2]), "+v"(cv.d[3]));
            Wb[tt][kk] = cv.h;
        }
    }

    // ---- precomputed LDS byte offsets
    char* ub = (char*)uf;
    const int rdo = lane * 16;
    int hwo[NTMAX];
#pragma unroll
    for (int tt = 0; tt < NTMAX; ++tt)
        hwo[tt] = fragoff(ln15, 112 + (t0 + tt) * 16 + 4 * q);

    // xe stager: threads 0..399, one float4 chunk each (spread over waves 0-6)
    const bool is_st = (tid < 400);
    const int  gr = tid / 25, gc = tid - gr * 25;
    const int  xwo = fragoff(gr & 15, gc * 4);
    __syncthreads();

    // ---- xe for t=0 into buffer 0; issue gather of xe for t=1 into pf
    float4 pf = {0.0f, 0.0f, 0.0f, 0.0f};
    if (is_st) {
        const int idx = xs[gr];
        const float4 f = ((const float4*)emb)[idx * 25 + gc];
        half4h hv; hv[0] = (_Float16)f.x; hv[1] = (_Float16)f.y;
                   hv[2] = (_Float16)f.z; hv[3] = (_Float16)f.w;
        *(half4h*)(ub + xwo) = hv;
        const int idx1 = xs[BM + gr];
        pf = ((const float4*)emb)[idx1 * 25 + gc];
    }
    __syncthreads();

    if (w < 3) {
        T_LOOP(3)
    } else {
        T_LOOP(2)
    }

    // ---- head: h1 = relu(h @ W1^T + b1); final h in buffer 0 (frag layout)
    {
        const int hro = fragoff(ln15, 112 + q * 8);
        floatx4 hacc[2];
        int ncol[2];
#pragma unroll
        for (int tt = 0; tt < 2; ++tt) {
            const int n = (w * 2 + tt) * 16 + ln15;
            ncol[tt] = n;
            const float b = b1[n];
            hacc[tt][0] = b; hacc[tt][1] = b; hacc[tt][2] = b; hacc[tt][3] = b;
        }
#pragma unroll
        for (int kk = 0; kk < NHF; ++kk) {
            const half8 a = *(const half8*)(ub + hro + kk * FB);
#pragma unroll
            for (int tt = 0; tt < 2; ++tt) {
                half8 bv;
#pragma unroll
                for (int j = 0; j < 8; ++j) {
                    const int k = kk * 32 + q * 8 + j;
                    bv[j] = (_Float16)((k < HID) ? W1[ncol[tt] * HID + k] : 0.0f);
                }
                hacc[tt] = __builtin_amdgcn_mfma_f32_16x16x32_f16(bv, a, hacc[tt], 0, 0, 0);
            }
        }
        // D transposed: lane ln15 = batch row, cols (2w+tt)*16 + 4q + r
#pragma unroll
        for (int tt = 0; tt < 2; ++tt) {
            float4 fv;
            fv.x = fmaxf(hacc[tt][0], 0.0f); fv.y = fmaxf(hacc[tt][1], 0.0f);
            fv.z = fmaxf(hacc[tt][2], 0.0f); fv.w = fmaxf(hacc[tt][3], 0.0f);
            *(float4*)&h1s[ln15][(w * 2 + tt) * 16 + 4 * q] = fv;
        }
    }
    __syncthreads();

    // ---- out = h1 @ W2^T + b2: 16 rows x 2 cols
    if (tid < 32) {
        const int r = tid & 15, o = tid >> 4;
        float a = b2[o];
        const float* ww = W2 + (size_t)o * NH1;
        for (int k = 0; k < NH1; ++k) a += h1s[r][k] * ww[k];
        out[(size_t)(row0 + r) * 2 + o] = a;
    }
}

extern "C" void kernel_launch(void* const* d_in, const int* in_sizes, int n_in,
                              void* d_out, int out_size, void* d_ws, size_t ws_size,
                              hipStream_t stream) {
    const int*   x    = (const int*)d_in[0];
    const float* emb  = (const float*)d_in[1];
    const float* W_ih = (const float*)d_in[2];
    const float* b_ih = (const float*)d_in[3];
    const float* W_hh = (const float*)d_in[4];
    const float* b_hh = (const float*)d_in[5];
    const float* W1   = (const float*)d_in[6];
    const float* b1   = (const float*)d_in[7];
    const float* W2   = (const float*)d_in[8];
    const float* b2   = (const float*)d_in[9];
    float* outp = (float*)d_out;

    hipLaunchKernelGGL(rnn_fused, dim3(BATCH / BM), dim3(512), 0, stream,
                       x, emb, W_ih, b_ih, W_hh, b_hh, W1, b1, W2, b2, outp);
}